// Round 2
// baseline (790.868 us; speedup 1.0000x reference)
//
#include <hip/hip_runtime.h>
#include <stdint.h>
#include <stddef.h>

// Problem dims (fixed)
#define NE    8
#define NT    2048
#define NDIN  2048
#define NDOUT 1408

typedef __bf16 bf16;
typedef __attribute__((ext_vector_type(8))) __bf16 bf16x8;
typedef __attribute__((ext_vector_type(4))) float f32x4;

static_assert(NDOUT % 128 == 0 && NDIN % 128 == 0 && NT % 128 == 0, "tile divisibility");

// ---- async global->LDS (16B/lane). LDS dest must be wave-uniform base; HW
// scatters lane i at base + 16*i. Direct C-style casts emit addrspacecast
// (generic->AS1 / generic->AS3), the documented-correct lowering.
__device__ __forceinline__ void gl_lds16(const void* g, void* lds) {
  __builtin_amdgcn_global_load_lds(
      (const __attribute__((address_space(1))) void*)g,
      (__attribute__((address_space(3))) void*)lds,
      16, 0, 0);
}

// ---------------- x fp32 -> bf16 (into d_out scratch) ----------------
__global__ void k_cvt_x(const float* __restrict__ x, bf16* __restrict__ xb) {
  const long n4 = (long)NE * NT * NDIN / 4;
  long i = (long)blockIdx.x * blockDim.x + threadIdx.x;
  const long stride = (long)gridDim.x * blockDim.x;
  for (; i < n4; i += stride) {
    float4 v = ((const float4*)x)[i];
    union { bf16 b[4]; uint64_t u; } p;
    p.b[0] = (bf16)v.x; p.b[1] = (bf16)v.y; p.b[2] = (bf16)v.z; p.b[3] = (bf16)v.w;
    ((uint64_t*)xb)[i] = p.u;
  }
}

// ------------- W [K][N] fp32 -> Wt [N][K] bf16 (per expert in z) -------------
__global__ void k_transpose(const float* __restrict__ W, bf16* __restrict__ Wt,
                            int K, int N) {
  __shared__ bf16 tile[32][34];  // +2 pad: conflict-free transposed reads
  const size_t mat = (size_t)K * N;
  const float* Wp = W + blockIdx.z * mat;
  bf16* Wtp = Wt + blockIdx.z * mat;
  const int n0 = blockIdx.x * 32, k0 = blockIdx.y * 32;
  const int tx = threadIdx.x & 31, ty = threadIdx.x >> 5;  // 32 x 8
#pragma unroll
  for (int i = 0; i < 4; i++) {
    int k = ty + i * 8;
    tile[k][tx] = (bf16)Wp[(size_t)(k0 + k) * N + n0 + tx];
  }
  __syncthreads();
#pragma unroll
  for (int i = 0; i < 4; i++) {
    int n = ty + i * 8;
    Wtp[(size_t)(n0 + n) * K + k0 + tx] = tile[tx][n];
  }
}

// ---------------- fused gate/down GEMM + SwiGLU -> h bf16 ----------------
#define BM 128
#define BN 128
#define BK 32

__global__ __launch_bounds__(256, 2) void k_gemm_swiglu(
    const bf16* __restrict__ xb,   // [E][T][DIN]
    const bf16* __restrict__ gt,   // [E][DOUT][DIN]  (gate^T, K-contig)
    const bf16* __restrict__ dt,   // [E][DOUT][DIN]
    bf16* __restrict__ h) {        // [E][T][DOUT]
  __shared__ __align__(16) bf16 As[BM * BK];
  __shared__ __align__(16) bf16 Bgs[BN * BK];
  __shared__ __align__(16) bf16 Bds[BN * BK];

  const int e = blockIdx.z;
  const int m0 = blockIdx.y * BM;
  const int n0 = blockIdx.x * BN;

  const bf16* Ap  = xb + ((size_t)e * NT + m0) * NDIN;
  const bf16* Bgp = gt + ((size_t)e * NDOUT + n0) * NDIN;
  const bf16* Bdp = dt + ((size_t)e * NDOUT + n0) * NDIN;

  const int lane = threadIdx.x & 63;
  const int wave = threadIdx.x >> 6;      // 4 waves, 2x2 -> 64x64 each
  const int wm = wave >> 1, wn = wave & 1;

  const int lrow = lane >> 2;             // staging: 4 lanes/row, 16 rows/issue
  const int lk   = (lane & 3) * 8;        // 8 bf16 = 16B per lane
  const int fr = lane & 15;               // fragment row/col
  const int fk = (lane >> 4) * 8;         // fragment k (contiguous 8, m92-verified)

  f32x4 accg[4][4], accu[4][4];
#pragma unroll
  for (int i = 0; i < 4; i++)
#pragma unroll
    for (int j = 0; j < 4; j++) {
      accg[i][j] = f32x4{0.f, 0.f, 0.f, 0.f};
      accu[i][j] = f32x4{0.f, 0.f, 0.f, 0.f};
    }

  for (int k0 = 0; k0 < NDIN; k0 += BK) {
#pragma unroll
    for (int i = 0; i < 2; i++) {
      const int r = wave * 32 + i * 16;   // 16 rows per issue per tile
      const size_t go = (size_t)(r + lrow) * NDIN + k0 + lk;
      gl_lds16(Ap + go,  As  + r * BK);
      gl_lds16(Bgp + go, Bgs + r * BK);
      gl_lds16(Bdp + go, Bds + r * BK);
    }
    __syncthreads();  // drains vmcnt, makes LDS visible

    bf16x8 af[4], bg[4], bd[4];
#pragma unroll
    for (int t = 0; t < 4; t++) {
      af[t] = *(const bf16x8*)(As  + (wm * 64 + t * 16 + fr) * BK + fk);
      bg[t] = *(const bf16x8*)(Bgs + (wn * 64 + t * 16 + fr) * BK + fk);
      bd[t] = *(const bf16x8*)(Bds + (wn * 64 + t * 16 + fr) * BK + fk);
    }
#pragma unroll
    for (int mt = 0; mt < 4; mt++)
#pragma unroll
      for (int nt = 0; nt < 4; nt++) {
        accg[mt][nt] = __builtin_amdgcn_mfma_f32_16x16x32_bf16(af[mt], bg[nt], accg[mt][nt], 0, 0, 0);
        accu[mt][nt] = __builtin_amdgcn_mfma_f32_16x16x32_bf16(af[mt], bd[nt], accu[mt][nt], 0, 0, 0);
      }
    __syncthreads();  // protect LDS before next-stage overwrite
  }

  // epilogue: h = silu(g) * u, bf16.  C/D: col=lane&15, row=(lane>>4)*4+reg
  bf16* hp = h + ((size_t)e * NT + m0) * NDOUT + n0;
  const int cc = lane & 15;
  const int cr = (lane >> 4) * 4;
#pragma unroll
  for (int mt = 0; mt < 4; mt++)
#pragma unroll
    for (int nt = 0; nt < 4; nt++) {
      f32x4 g4 = accg[mt][nt], u4 = accu[mt][nt];
#pragma unroll
      for (int r = 0; r < 4; r++) {
        float gg = g4[r];
        float s = gg / (1.f + __expf(-gg));
        float hh = s * u4[r];
        hp[(size_t)(wm * 64 + mt * 16 + cr + r) * NDOUT + wn * 64 + nt * 16 + cc] = (bf16)hh;
      }
    }
}

// ---------------- out = h @ up^T -> fp32 ----------------
__global__ __launch_bounds__(256, 2) void k_gemm_out(
    const bf16* __restrict__ hb,   // [E][T][DOUT]
    const bf16* __restrict__ ut,   // [E][DIN][DOUT]  (up^T, K-contig)
    float* __restrict__ out) {     // [E][T][DIN]
  __shared__ __align__(16) bf16 As[BM * BK];
  __shared__ __align__(16) bf16 Bs[BN * BK];

  const int e = blockIdx.z;
  const int m0 = blockIdx.y * BM;
  const int n0 = blockIdx.x * BN;

  const bf16* Ap = hb + ((size_t)e * NT + m0) * NDOUT;
  const bf16* Bp = ut + ((size_t)e * NDIN + n0) * NDOUT;

  const int lane = threadIdx.x & 63;
  const int wave = threadIdx.x >> 6;
  const int wm = wave >> 1, wn = wave & 1;
  const int lrow = lane >> 2;
  const int lk   = (lane & 3) * 8;
  const int fr = lane & 15;
  const int fk = (lane >> 4) * 8;

  f32x4 acc[4][4];
#pragma unroll
  for (int i = 0; i < 4; i++)
#pragma unroll
    for (int j = 0; j < 4; j++) acc[i][j] = f32x4{0.f, 0.f, 0.f, 0.f};

  for (int k0 = 0; k0 < NDOUT; k0 += BK) {
#pragma unroll
    for (int i = 0; i < 2; i++) {
      const int r = wave * 32 + i * 16;
      const size_t go = (size_t)(r + lrow) * NDOUT + k0 + lk;
      gl_lds16(Ap + go, As + r * BK);
      gl_lds16(Bp + go, Bs + r * BK);
    }
    __syncthreads();

    bf16x8 af[4], bfr[4];
#pragma unroll
    for (int t = 0; t < 4; t++) {
      af[t]  = *(const bf16x8*)(As + (wm * 64 + t * 16 + fr) * BK + fk);
      bfr[t] = *(const bf16x8*)(Bs + (wn * 64 + t * 16 + fr) * BK + fk);
    }
#pragma unroll
    for (int mt = 0; mt < 4; mt++)
#pragma unroll
      for (int nt = 0; nt < 4; nt++)
        acc[mt][nt] = __builtin_amdgcn_mfma_f32_16x16x32_bf16(af[mt], bfr[nt], acc[mt][nt], 0, 0, 0);
    __syncthreads();
  }

  float* op = out + ((size_t)e * NT + m0) * NDIN + n0;
  const int cc = lane & 15;
  const int cr = (lane >> 4) * 4;
#pragma unroll
  for (int mt = 0; mt < 4; mt++)
#pragma unroll
    for (int nt = 0; nt < 4; nt++) {
#pragma unroll
      for (int r = 0; r < 4; r++)
        op[(size_t)(wm * 64 + mt * 16 + cr + r) * NDIN + wn * 64 + nt * 16 + cc] =
            acc[mt][nt][r];
    }
}

// ---------------- launch ----------------
extern "C" void kernel_launch(void* const* d_in, const int* in_sizes, int n_in,
                              void* d_out, int out_size, void* d_ws, size_t ws_size,
                              hipStream_t stream) {
  const float* x    = (const float*)d_in[0];
  const float* gate = (const float*)d_in[1];
  const float* down = (const float*)d_in[2];
  const float* up   = (const float*)d_in[3];

  // d_out (134 MB fp32) doubles as scratch for x_bf16 (67 MB) until the final GEMM.
  bf16* xb = (bf16*)d_out;

  // ws layout: gate_t | down_t | up_t | h   (4 x 46.1 MB = 184.5 MB)
  const size_t WE = (size_t)NE * NDOUT * NDIN;  // elems per tensor
  bf16* gate_t = (bf16*)d_ws;
  bf16* down_t = gate_t + WE;
  bf16* up_t   = down_t + WE;
  bf16* hbuf   = up_t + WE;

  k_cvt_x<<<2048, 256, 0, stream>>>(x, xb);
  // gate/down: [K=DIN][N=DOUT] -> [DOUT][DIN]
  k_transpose<<<dim3(NDOUT / 32, NDIN / 32, NE), 256, 0, stream>>>(gate, gate_t, NDIN, NDOUT);
  k_transpose<<<dim3(NDOUT / 32, NDIN / 32, NE), 256, 0, stream>>>(down, down_t, NDIN, NDOUT);
  // up: [K=DOUT][N=DIN] -> [DIN][DOUT]
  k_transpose<<<dim3(NDIN / 32, NDOUT / 32, NE), 256, 0, stream>>>(up, up_t, NDOUT, NDIN);

  k_gemm_swiglu<<<dim3(NDOUT / BN, NT / BM, NE), 256, 0, stream>>>(xb, gate_t, down_t, hbuf);
  k_gemm_out<<<dim3(NDIN / BN, NT / BM, NE), 256, 0, stream>>>(hbuf, up_t, (float*)d_out);
}

// Round 3
// 758.321 us; speedup vs baseline: 1.0429x; 1.0429x over previous
//
#include <hip/hip_runtime.h>
#include <stdint.h>
#include <stddef.h>

// Problem dims (fixed)
#define NE    8
#define NT    2048
#define NDIN  2048
#define NDOUT 1408

typedef __bf16 bf16;
typedef __attribute__((ext_vector_type(8))) __bf16 bf16x8;
typedef __attribute__((ext_vector_type(4))) float f32x4;

#define BM 128
#define BN 128
#define BK 32

#define NTM   (NT / BM)      // 16 m-tiles
#define NTN1  (NDOUT / BN)   // 11 n-tiles (swiglu)
#define NTN2  (NDIN / BN)    // 16 n-tiles (out gemm)

static_assert(NDOUT % 128 == 0 && NDIN % 128 == 0 && NT % 128 == 0, "tile divisibility");
static_assert(NDOUT % 32 == 0 && NDIN % 32 == 0, "transpose divisibility");

// ---- async global->LDS (16B/lane). LDS dest is wave-uniform base; HW scatters
// lane i at base + 16*i.
__device__ __forceinline__ void gl_lds16(const void* g, void* lds) {
  __builtin_amdgcn_global_load_lds(
      (const __attribute__((address_space(1))) void*)g,
      (__attribute__((address_space(3))) void*)lds,
      16, 0, 0);
}

// ---------------- x fp32 -> bf16 (into d_out scratch) ----------------
__global__ void k_cvt_x(const float* __restrict__ x, bf16* __restrict__ xb) {
  const long n4 = (long)NE * NT * NDIN / 4;
  long i = (long)blockIdx.x * blockDim.x + threadIdx.x;
  const long stride = (long)gridDim.x * blockDim.x;
  for (; i < n4; i += stride) {
    float4 v = ((const float4*)x)[i];
    union { bf16 b[4]; uint64_t u; } p;
    p.b[0] = (bf16)v.x; p.b[1] = (bf16)v.y; p.b[2] = (bf16)v.z; p.b[3] = (bf16)v.w;
    ((uint64_t*)xb)[i] = p.u;
  }
}

// ------------- W [K][N] fp32 -> Wt [N][K] bf16 (per expert in z) -------------
// 128(K) x 32(N) tile: reads 128B-coalesced per k-row, writes 256B-contiguous
// per n-row via bf16x8 (16B/lane).
__global__ void k_transpose(const float* __restrict__ W, bf16* __restrict__ Wt,
                            int K, int N) {
  __shared__ bf16 tile[128][34];  // [k][n], +2 pad
  const size_t mat = (size_t)K * N;
  const float* Wp = W + blockIdx.z * mat;
  bf16* Wtp = Wt + blockIdx.z * mat;
  const int n0 = blockIdx.x * 32, k0 = blockIdx.y * 128;
  const int tn = threadIdx.x & 31, tk = threadIdx.x >> 5;  // 32 lanes/row, 8 rows/pass
#pragma unroll
  for (int i = 0; i < 16; i++) {
    int k = tk + i * 8;
    tile[k][tn] = (bf16)Wp[(size_t)(k0 + k) * N + n0 + tn];
  }
  __syncthreads();
  const int wn = threadIdx.x >> 4, wkk = (threadIdx.x & 15) * 8;  // 16 lanes/row
#pragma unroll
  for (int i = 0; i < 2; i++) {
    int n = wn + i * 16;
    union { bf16 b[8]; bf16x8 v; } p;
#pragma unroll
    for (int j = 0; j < 8; j++) p.b[j] = tile[wkk + j][n];
    *(bf16x8*)(Wtp + (size_t)(n0 + n) * K + k0 + wkk) = p.v;
  }
}

// ---------------- fused gate/down GEMM + SwiGLU -> h bf16 ----------------
// 1D grid, expert = lin & 7 so each XCD (round-robin by linear block id) owns
// one expert -> L2 sees a single expert's working set.
__global__ __launch_bounds__(256, 2) void k_gemm_swiglu(
    const bf16* __restrict__ xb,   // [E][T][DIN]
    const bf16* __restrict__ gt,   // [E][DOUT][DIN]  (gate^T, K-contig)
    const bf16* __restrict__ dt,   // [E][DOUT][DIN]
    bf16* __restrict__ h) {        // [E][T][DOUT]
  __shared__ __align__(16) bf16 As[BM * BK];
  __shared__ __align__(16) bf16 Bgs[BN * BK];
  __shared__ __align__(16) bf16 Bds[BN * BK];

  const int lin = blockIdx.x;
  const int e = lin & 7;
  const int idx = lin >> 3;            // 0..NTM*NTN1-1, n fastest
  const int m0 = (idx / NTN1) * BM;
  const int n0 = (idx % NTN1) * BN;

  const bf16* Ap  = xb + ((size_t)e * NT + m0) * NDIN;
  const bf16* Bgp = gt + ((size_t)e * NDOUT + n0) * NDIN;
  const bf16* Bdp = dt + ((size_t)e * NDOUT + n0) * NDIN;

  const int lane = threadIdx.x & 63;
  const int wave = threadIdx.x >> 6;      // 4 waves, 2x2 -> 64x64 each
  const int wm = wave >> 1, wn = wave & 1;

  const int lrow = lane >> 2;             // staging: 4 lanes/row, 16 rows/issue
  const int lk   = (lane & 3) * 8;        // 8 bf16 = 16B per lane
  const int fr = lane & 15;               // fragment row/col
  const int fk = (lane >> 4) * 8;         // fragment k (contiguous 8)

  f32x4 accg[4][4], accu[4][4];
#pragma unroll
  for (int i = 0; i < 4; i++)
#pragma unroll
    for (int j = 0; j < 4; j++) {
      accg[i][j] = f32x4{0.f, 0.f, 0.f, 0.f};
      accu[i][j] = f32x4{0.f, 0.f, 0.f, 0.f};
    }

  for (int k0 = 0; k0 < NDIN; k0 += BK) {
#pragma unroll
    for (int i = 0; i < 2; i++) {
      const int r = wave * 32 + i * 16;   // 16 rows per issue per tile
      const size_t go = (size_t)(r + lrow) * NDIN + k0 + lk;
      gl_lds16(Ap + go,  As  + r * BK);
      gl_lds16(Bgp + go, Bgs + r * BK);
      gl_lds16(Bdp + go, Bds + r * BK);
    }
    __syncthreads();  // drains vmcnt, makes LDS visible

    bf16x8 af[4], bg[4], bd[4];
#pragma unroll
    for (int t = 0; t < 4; t++) {
      af[t] = *(const bf16x8*)(As  + (wm * 64 + t * 16 + fr) * BK + fk);
      bg[t] = *(const bf16x8*)(Bgs + (wn * 64 + t * 16 + fr) * BK + fk);
      bd[t] = *(const bf16x8*)(Bds + (wn * 64 + t * 16 + fr) * BK + fk);
    }
#pragma unroll
    for (int mt = 0; mt < 4; mt++)
#pragma unroll
      for (int nt = 0; nt < 4; nt++) {
        accg[mt][nt] = __builtin_amdgcn_mfma_f32_16x16x32_bf16(af[mt], bg[nt], accg[mt][nt], 0, 0, 0);
        accu[mt][nt] = __builtin_amdgcn_mfma_f32_16x16x32_bf16(af[mt], bd[nt], accu[mt][nt], 0, 0, 0);
      }
    __syncthreads();  // protect LDS before next-stage overwrite
  }

  // epilogue: h = silu(g) * u, bf16.  C/D: col=lane&15, row=(lane>>4)*4+reg
  bf16* hp = h + ((size_t)e * NT + m0) * NDOUT + n0;
  const int cc = lane & 15;
  const int cr = (lane >> 4) * 4;
#pragma unroll
  for (int mt = 0; mt < 4; mt++)
#pragma unroll
    for (int nt = 0; nt < 4; nt++) {
      f32x4 g4 = accg[mt][nt], u4 = accu[mt][nt];
#pragma unroll
      for (int r = 0; r < 4; r++) {
        float gg = g4[r];
        float s = gg / (1.f + __expf(-gg));
        float hh = s * u4[r];
        hp[(size_t)(wm * 64 + mt * 16 + cr + r) * NDOUT + wn * 64 + nt * 16 + cc] = (bf16)hh;
      }
    }
}

// ---------------- out = h @ up^T -> fp32 ----------------
__global__ __launch_bounds__(256, 2) void k_gemm_out(
    const bf16* __restrict__ hb,   // [E][T][DOUT]
    const bf16* __restrict__ ut,   // [E][DIN][DOUT]  (up^T, K-contig)
    float* __restrict__ out) {     // [E][T][DIN]
  __shared__ __align__(16) bf16 As[BM * BK];
  __shared__ __align__(16) bf16 Bs[BN * BK];

  const int lin = blockIdx.x;
  const int e = lin & 7;
  const int idx = lin >> 3;            // n fastest
  const int m0 = (idx / NTN2) * BM;
  const int n0 = (idx % NTN2) * BN;

  const bf16* Ap = hb + ((size_t)e * NT + m0) * NDOUT;
  const bf16* Bp = ut + ((size_t)e * NDIN + n0) * NDOUT;

  const int lane = threadIdx.x & 63;
  const int wave = threadIdx.x >> 6;
  const int wm = wave >> 1, wn = wave & 1;
  const int lrow = lane >> 2;
  const int lk   = (lane & 3) * 8;
  const int fr = lane & 15;
  const int fk = (lane >> 4) * 8;

  f32x4 acc[4][4];
#pragma unroll
  for (int i = 0; i < 4; i++)
#pragma unroll
    for (int j = 0; j < 4; j++) acc[i][j] = f32x4{0.f, 0.f, 0.f, 0.f};

  for (int k0 = 0; k0 < NDOUT; k0 += BK) {
#pragma unroll
    for (int i = 0; i < 2; i++) {
      const int r = wave * 32 + i * 16;
      const size_t go = (size_t)(r + lrow) * NDOUT + k0 + lk;
      gl_lds16(Ap + go, As + r * BK);
      gl_lds16(Bp + go, Bs + r * BK);
    }
    __syncthreads();

    bf16x8 af[4], bfr[4];
#pragma unroll
    for (int t = 0; t < 4; t++) {
      af[t]  = *(const bf16x8*)(As + (wm * 64 + t * 16 + fr) * BK + fk);
      bfr[t] = *(const bf16x8*)(Bs + (wn * 64 + t * 16 + fr) * BK + fk);
    }
#pragma unroll
    for (int mt = 0; mt < 4; mt++)
#pragma unroll
      for (int nt = 0; nt < 4; nt++)
        acc[mt][nt] = __builtin_amdgcn_mfma_f32_16x16x32_bf16(af[mt], bfr[nt], acc[mt][nt], 0, 0, 0);
    __syncthreads();
  }

  float* op = out + ((size_t)e * NT + m0) * NDIN + n0;
  const int cc = lane & 15;
  const int cr = (lane >> 4) * 4;
#pragma unroll
  for (int mt = 0; mt < 4; mt++)
#pragma unroll
    for (int nt = 0; nt < 4; nt++) {
#pragma unroll
      for (int r = 0; r < 4; r++)
        op[(size_t)(wm * 64 + mt * 16 + cr + r) * NDIN + wn * 64 + nt * 16 + cc] =
            acc[mt][nt][r];
    }
}

// ---------------- launch ----------------
extern "C" void kernel_launch(void* const* d_in, const int* in_sizes, int n_in,
                              void* d_out, int out_size, void* d_ws, size_t ws_size,
                              hipStream_t stream) {
  const float* x    = (const float*)d_in[0];
  const float* gate = (const float*)d_in[1];
  const float* down = (const float*)d_in[2];
  const float* up   = (const float*)d_in[3];

  // d_out (134 MB fp32) doubles as scratch for x_bf16 (67 MB) until the final GEMM.
  bf16* xb = (bf16*)d_out;

  // ws layout: gate_t | down_t | up_t | h   (4 x 46.1 MB = 184.5 MB)
  const size_t WE = (size_t)NE * NDOUT * NDIN;  // elems per tensor
  bf16* gate_t = (bf16*)d_ws;
  bf16* down_t = gate_t + WE;
  bf16* up_t   = down_t + WE;
  bf16* hbuf   = up_t + WE;

  k_cvt_x<<<2048, 256, 0, stream>>>(x, xb);
  // gate/down: [K=DIN][N=DOUT] -> [DOUT][DIN]
  k_transpose<<<dim3(NDOUT / 32, NDIN / 128, NE), 256, 0, stream>>>(gate, gate_t, NDIN, NDOUT);
  k_transpose<<<dim3(NDOUT / 32, NDIN / 128, NE), 256, 0, stream>>>(down, down_t, NDIN, NDOUT);
  // up: [K=DOUT][N=DIN] -> [DIN][DOUT]
  k_transpose<<<dim3(NDIN / 32, NDOUT / 128, NE), 256, 0, stream>>>(up, up_t, NDOUT, NDIN);

  k_gemm_swiglu<<<NTM * NTN1 * NE, 256, 0, stream>>>(xb, gate_t, down_t, hbuf);
  k_gemm_out<<<NTM * NTN2 * NE, 256, 0, stream>>>(hbuf, up_t, (float*)d_out);
}

// Round 5
// 747.782 us; speedup vs baseline: 1.0576x; 1.0141x over previous
//
#include <hip/hip_runtime.h>
#include <stdint.h>
#include <stddef.h>

// Problem dims (fixed)
#define NE    8
#define NT    2048
#define NDIN  2048
#define NDOUT 1408

typedef __bf16 bf16;
typedef __attribute__((ext_vector_type(8))) __bf16 bf16x8;
typedef __attribute__((ext_vector_type(4))) float f32x4;

#define BM 128
#define BN 128
#define BK 32

#define NTM   (NT / BM)      // 16 m-tiles
#define NTN1  (NDOUT / BN)   // 11 n-tiles (swiglu)
#define NTN2  (NDIN / BN)    // 16 n-tiles (out gemm)

static_assert(NDOUT % 128 == 0 && NDIN % 128 == 0 && NT % 128 == 0, "tile divisibility");
// transpose tiling: 128 K x 64 N per block; both weight shapes give 352 tiles
static_assert((NDIN / 128) * (NDOUT / 64) == 352, "gate/down tiles");
static_assert((NDOUT / 128) * (NDIN / 64) == 352, "up tiles");

// ---- async global->LDS (16B/lane). LDS dest is wave-uniform base; HW scatters
// lane i at base + 16*i.
__device__ __forceinline__ void gl_lds16(const void* g, void* lds) {
  __builtin_amdgcn_global_load_lds(
      (const __attribute__((address_space(1))) void*)g,
      (__attribute__((address_space(3))) void*)lds,
      16, 0, 0);
}

__device__ __forceinline__ uint32_t pk_bf16(float lo, float hi) {
  union { bf16 b; uint16_t s; } a, c;
  a.b = (bf16)lo; c.b = (bf16)hi;
  return (uint32_t)a.s | ((uint32_t)c.s << 16);
}

// ---------------- x fp32 -> bf16 (into d_out scratch) ----------------
__global__ void k_cvt_x(const float* __restrict__ x, bf16* __restrict__ xb) {
  const long n4 = (long)NE * NT * NDIN / 4;
  long i = (long)blockIdx.x * blockDim.x + threadIdx.x;
  const long stride = (long)gridDim.x * blockDim.x;
  for (; i < n4; i += stride) {
    float4 v = ((const float4*)x)[i];
    union { bf16 b[4]; uint64_t u; } p;
    p.b[0] = (bf16)v.x; p.b[1] = (bf16)v.y; p.b[2] = (bf16)v.z; p.b[3] = (bf16)v.w;
    ((uint64_t*)xb)[i] = p.u;
  }
}

// ---- all-weights transpose+cvt: W [K][N] fp32 -> Wt [N][K] bf16 ----
// One kernel, grid (352, 24): y -> {type 0=gate,1=down,2=up} x {expert}.
// Tile 128(K) x 64(N). Trick: pack bf16(W[2kk][n]),bf16(W[2kk+1][n]) into a
// u32; transposing the u32 matrix [64kk][64n] yields [N][K] bf16 directly.
// Reads: float4 (1KB/wave-instr). Writes: uint4 (16B/lane, 256B/row run).
// LDS [64][65] u32: both scalar phases <=2-way bank alias (free).
__global__ __launch_bounds__(256) void k_transpose_all(
    const float* __restrict__ g, const float* __restrict__ d,
    const float* __restrict__ u,
    bf16* __restrict__ gt, bf16* __restrict__ dt, bf16* __restrict__ ut) {
  __shared__ uint32_t lds[64][65];
  const int z = blockIdx.y;
  const int type = z >> 3, e = z & 7;
  int K, N;
  const float* W;
  bf16* Wt;
  if (type == 0)      { K = NDIN;  N = NDOUT; W = g; Wt = gt; }
  else if (type == 1) { K = NDIN;  N = NDOUT; W = d; Wt = dt; }
  else                { K = NDOUT; N = NDIN;  W = u; Wt = ut; }
  const int ntn = N >> 6;
  const int kt = blockIdx.x / ntn, nt = blockIdx.x % ntn;
  const int k0 = kt * 128, n0 = nt * 64;
  const float* Wp = W + (size_t)e * K * N;
  bf16* Wtp = Wt + (size_t)e * K * N;

  const int tg = threadIdx.x >> 4;   // 0..15
  const int q  = threadIdx.x & 15;   // 0..15

#pragma unroll
  for (int i = 0; i < 4; i++) {
    const int kk = tg + 16 * i;      // u32-row = k-pair index
    const float4 a = *(const float4*)(Wp + (size_t)(k0 + 2 * kk)     * N + n0 + 4 * q);
    const float4 b = *(const float4*)(Wp + (size_t)(k0 + 2 * kk + 1) * N + n0 + 4 * q);
    lds[kk][4 * q + 0] = pk_bf16(a.x, b.x);
    lds[kk][4 * q + 1] = pk_bf16(a.y, b.y);
    lds[kk][4 * q + 2] = pk_bf16(a.z, b.z);
    lds[kk][4 * q + 3] = pk_bf16(a.w, b.w);
  }
  __syncthreads();
#pragma unroll
  for (int i = 0; i < 4; i++) {
    const int nn = tg + 16 * i;      // output row (n)
    uint4 v;
    v.x = lds[4 * q + 0][nn];
    v.y = lds[4 * q + 1][nn];
    v.z = lds[4 * q + 2][nn];
    v.w = lds[4 * q + 3][nn];
    *(uint4*)(Wtp + (size_t)(n0 + nn) * K + k0 + 8 * q) = v;
  }
}

// ---------------- fused gate/down GEMM + SwiGLU -> h bf16 ----------------
// 1D grid, expert = lin & 7 so each XCD (round-robin by linear block id) owns
// one expert -> L2 sees a single expert's working set.
__global__ __launch_bounds__(256, 2) void k_gemm_swiglu(
    const bf16* __restrict__ xb,   // [E][T][DIN]
    const bf16* __restrict__ gt,   // [E][DOUT][DIN]  (gate^T, K-contig)
    const bf16* __restrict__ dt,   // [E][DOUT][DIN]
    bf16* __restrict__ h) {        // [E][T][DOUT]
  __shared__ __align__(16) bf16 As[BM * BK];
  __shared__ __align__(16) bf16 Bgs[BN * BK];
  __shared__ __align__(16) bf16 Bds[BN * BK];

  const int lin = blockIdx.x;
  const int e = lin & 7;
  const int idx = lin >> 3;            // 0..NTM*NTN1-1, n fastest
  const int m0 = (idx / NTN1) * BM;
  const int n0 = (idx % NTN1) * BN;

  const bf16* Ap  = xb + ((size_t)e * NT + m0) * NDIN;
  const bf16* Bgp = gt + ((size_t)e * NDOUT + n0) * NDIN;
  const bf16* Bdp = dt + ((size_t)e * NDOUT + n0) * NDIN;

  const int lane = threadIdx.x & 63;
  const int wave = threadIdx.x >> 6;      // 4 waves, 2x2 -> 64x64 each
  const int wm = wave >> 1, wn = wave & 1;

  const int lrow = lane >> 2;             // staging: 4 lanes/row, 16 rows/issue
  const int lk   = (lane & 3) * 8;        // 8 bf16 = 16B per lane
  const int fr = lane & 15;               // fragment row/col
  const int fk = (lane >> 4) * 8;         // fragment k (contiguous 8)

  f32x4 accg[4][4], accu[4][4];
#pragma unroll
  for (int i = 0; i < 4; i++)
#pragma unroll
    for (int j = 0; j < 4; j++) {
      accg[i][j] = f32x4{0.f, 0.f, 0.f, 0.f};
      accu[i][j] = f32x4{0.f, 0.f, 0.f, 0.f};
    }

  for (int k0 = 0; k0 < NDIN; k0 += BK) {
#pragma unroll
    for (int i = 0; i < 2; i++) {
      const int r = wave * 32 + i * 16;   // 16 rows per issue per tile
      const size_t go = (size_t)(r + lrow) * NDIN + k0 + lk;
      gl_lds16(Ap + go,  As  + r * BK);
      gl_lds16(Bgp + go, Bgs + r * BK);
      gl_lds16(Bdp + go, Bds + r * BK);
    }
    __syncthreads();  // drains vmcnt, makes LDS visible

    bf16x8 af[4], bg[4], bd[4];
#pragma unroll
    for (int t = 0; t < 4; t++) {
      af[t] = *(const bf16x8*)(As  + (wm * 64 + t * 16 + fr) * BK + fk);
      bg[t] = *(const bf16x8*)(Bgs + (wn * 64 + t * 16 + fr) * BK + fk);
      bd[t] = *(const bf16x8*)(Bds + (wn * 64 + t * 16 + fr) * BK + fk);
    }
#pragma unroll
    for (int mt = 0; mt < 4; mt++)
#pragma unroll
      for (int nt = 0; nt < 4; nt++) {
        accg[mt][nt] = __builtin_amdgcn_mfma_f32_16x16x32_bf16(af[mt], bg[nt], accg[mt][nt], 0, 0, 0);
        accu[mt][nt] = __builtin_amdgcn_mfma_f32_16x16x32_bf16(af[mt], bd[nt], accu[mt][nt], 0, 0, 0);
      }
    __syncthreads();  // protect LDS before next-stage overwrite
  }

  // epilogue: h = silu(g) * u, bf16.  C/D: col=lane&15, row=(lane>>4)*4+reg
  bf16* hp = h + ((size_t)e * NT + m0) * NDOUT + n0;
  const int cc = lane & 15;
  const int cr = (lane >> 4) * 4;
#pragma unroll
  for (int mt = 0; mt < 4; mt++)
#pragma unroll
    for (int nt = 0; nt < 4; nt++) {
      f32x4 g4 = accg[mt][nt], u4 = accu[mt][nt];
#pragma unroll
      for (int r = 0; r < 4; r++) {
        float gg = g4[r];
        float s = gg / (1.f + __expf(-gg));
        float hh = s * u4[r];
        hp[(size_t)(wm * 64 + mt * 16 + cr + r) * NDOUT + wn * 64 + nt * 16 + cc] = (bf16)hh;
      }
    }
}

// ---------------- out = h @ up^T -> fp32 ----------------
__global__ __launch_bounds__(256, 2) void k_gemm_out(
    const bf16* __restrict__ hb,   // [E][T][DOUT]
    const bf16* __restrict__ ut,   // [E][DIN][DOUT]  (up^T, K-contig)
    float* __restrict__ out) {     // [E][T][DIN]
  __shared__ __align__(16) bf16 As[BM * BK];
  __shared__ __align__(16) bf16 Bs[BN * BK];

  const int lin = blockIdx.x;
  const int e = lin & 7;
  const int idx = lin >> 3;            // n fastest
  const int m0 = (idx / NTN2) * BM;
  const int n0 = (idx % NTN2) * BN;

  const bf16* Ap = hb + ((size_t)e * NT + m0) * NDOUT;
  const bf16* Bp = ut + ((size_t)e * NDIN + n0) * NDOUT;

  const int lane = threadIdx.x & 63;
  const int wave = threadIdx.x >> 6;
  const int wm = wave >> 1, wn = wave & 1;
  const int lrow = lane >> 2;
  const int lk   = (lane & 3) * 8;
  const int fr = lane & 15;
  const int fk = (lane >> 4) * 8;

  f32x4 acc[4][4];
#pragma unroll
  for (int i = 0; i < 4; i++)
#pragma unroll
    for (int j = 0; j < 4; j++) acc[i][j] = f32x4{0.f, 0.f, 0.f, 0.f};

  for (int k0 = 0; k0 < NDOUT; k0 += BK) {
#pragma unroll
    for (int i = 0; i < 2; i++) {
      const int r = wave * 32 + i * 16;
      const size_t go = (size_t)(r + lrow) * NDOUT + k0 + lk;
      gl_lds16(Ap + go, As + r * BK);
      gl_lds16(Bp + go, Bs + r * BK);
    }
    __syncthreads();

    bf16x8 af[4], bfr[4];
#pragma unroll
    for (int t = 0; t < 4; t++) {
      af[t]  = *(const bf16x8*)(As + (wm * 64 + t * 16 + fr) * BK + fk);
      bfr[t] = *(const bf16x8*)(Bs + (wn * 64 + t * 16 + fr) * BK + fk);
    }
#pragma unroll
    for (int mt = 0; mt < 4; mt++)
#pragma unroll
      for (int nt = 0; nt < 4; nt++)
        acc[mt][nt] = __builtin_amdgcn_mfma_f32_16x16x32_bf16(af[mt], bfr[nt], acc[mt][nt], 0, 0, 0);
    __syncthreads();
  }

  float* op = out + ((size_t)e * NT + m0) * NDIN + n0;
  const int cc = lane & 15;
  const int cr = (lane >> 4) * 4;
#pragma unroll
  for (int mt = 0; mt < 4; mt++)
#pragma unroll
    for (int nt = 0; nt < 4; nt++) {
#pragma unroll
      for (int r = 0; r < 4; r++)
        op[(size_t)(wm * 64 + mt * 16 + cr + r) * NDIN + wn * 64 + nt * 16 + cc] =
            acc[mt][nt][r];
    }
}

// ---------------- launch ----------------
extern "C" void kernel_launch(void* const* d_in, const int* in_sizes, int n_in,
                              void* d_out, int out_size, void* d_ws, size_t ws_size,
                              hipStream_t stream) {
  const float* x    = (const float*)d_in[0];
  const float* gate = (const float*)d_in[1];
  const float* down = (const float*)d_in[2];
  const float* up   = (const float*)d_in[3];

  // d_out (134 MB fp32) doubles as scratch for x_bf16 (67 MB) until the final GEMM.
  bf16* xb = (bf16*)d_out;

  // ws layout: gate_t | down_t | up_t | h   (4 x 46.1 MB = 184.5 MB)
  const size_t WE = (size_t)NE * NDOUT * NDIN;  // elems per tensor
  bf16* gate_t = (bf16*)d_ws;
  bf16* down_t = gate_t + WE;
  bf16* up_t   = down_t + WE;
  bf16* hbuf   = up_t + WE;

  k_cvt_x<<<2048, 256, 0, stream>>>(x, xb);
  k_transpose_all<<<dim3(352, 24), 256, 0, stream>>>(gate, down, up,
                                                     gate_t, down_t, up_t);

  k_gemm_swiglu<<<NTM * NTN1 * NE, 256, 0, stream>>>(xb, gate_t, down_t, hbuf);
  k_gemm_out<<<NTM * NTN2 * NE, 256, 0, stream>>>(hbuf, up_t, (float*)d_out);
}